// Round 3
// baseline (228.331 us; speedup 1.0000x reference)
//
#include <hip/hip_runtime.h>
#include <hip/hip_bf16.h>

#define NN 50000
#define EE 800000
#define CC 64
#define HH 2
#define LL 3
#define CAP 64     // slots per node (Poisson(16): P(>=64) ~ 1e-13)

// ---------------- build ----------------
// R14: direct-atomic build. The R11 counting sort avoided contended atomics,
// but contention was on the 782 BUCKET counters (~1000 collisions each);
// per-node cnt[50000] sees ~16 contenders/address spread over all L2 slices.
// One coalesced 6.4MB read + 800k low-contention atomics + scattered 2B
// writes replaces: stash/hist LDS traffic + 3.2MB bucket write + 3.2MB
// re-read + 800k LDS rank atomics (two kernels -> one).

__global__ __launch_bounds__(256) void k_build(const int* __restrict__ ei,
                                               int* __restrict__ cnt,
                                               unsigned short* __restrict__ slots) {
    int k = blockIdx.x * 256 + threadIdx.x;
    if (k >= EE) return;
    int s = ei[k];
    int d = ei[EE + k];
    int pos = atomicAdd(&cnt[d], 1);
    if (pos < CAP) slots[(size_t)d * CAP + pos] = (unsigned short)s;
}

// ---------------- fused GAT layer ----------------
// R13 structure (proven 200us): wave per node; 4 subgroups x 16 lanes; lane
// holds one channel quad -> ONE contiguous dwordx4 per row per lane (proven
// coalescing). Per-edge reduce via fused v_add_f32_dpp (VALU pipe, no lgkm
// stall): quad_perm/quad_perm/row_half_mirror/row_mirror. Cross-subgroup
// merge keeps __shfl_xor (DPP cannot cross 16-lane rows).

#define LEAKY(v) fmaxf((v), 0.2f * (v))

template <int CTRL>
__device__ __forceinline__ float dpp_add(float v) {
    int t = __builtin_amdgcn_update_dpp(0, __float_as_int(v), CTRL, 0xF, 0xF, true);
    return v + __int_as_float(t);
}

// sum over the 16 lanes of a subgroup (subgroups are 16-lane aligned)
__device__ __forceinline__ float red16(float v) {
    v = dpp_add<0xB1>(v);    // quad_perm [1,0,3,2] = lane^1
    v = dpp_add<0x4E>(v);    // quad_perm [2,3,0,1] = lane^2
    v = dpp_add<0x141>(v);   // row_half_mirror     = lane^4 (quads uniform)
    v = dpp_add<0x140>(v);   // row_mirror          = lane^8 (halves uniform)
    return v;
}

template <bool FIRST>
__global__ __launch_bounds__(256) void k_gat(const float* __restrict__ h,
                                             const int* __restrict__ cnt,
                                             const unsigned short* __restrict__ slots,
                                             const float* __restrict__ att_l,
                                             const float* __restrict__ bias_l,
                                             float* __restrict__ h_out,
                                             float* __restrict__ acc, int n) {
    int wid = threadIdx.x >> 6;
    int lane = threadIdx.x & 63;
    int node = blockIdx.x * 4 + wid;
    if (node >= n) return;
    int sub = lane >> 4, q = lane & 15;
    unsigned qb = (unsigned)q << 4;              // byte offset of quad in a row
    const char* hb = (const char*)h;
    float4 a0q = ((const float4*)att_l)[q];
    float4 a1q = ((const float4*)att_l)[16 + q];
    float4 hd = *(const float4*)(hb + (((unsigned)node << 8) + qb));
    int deg = cnt[node];
    if (deg > CAP) deg = CAP;
    const unsigned* rowu = (const unsigned*)(slots + (size_t)node * CAP);

    float s0, s1;
    float4 A0, A1;

    // self-loop: all 4 subgroups, weight 1/4 (merge sums restore 1x) — no branch
    {
        float vx = LEAKY(2.f * hd.x), vy = LEAKY(2.f * hd.y);
        float vz = LEAKY(2.f * hd.z), vw = LEAKY(2.f * hd.w);
        float p0 = vx * a0q.x + vy * a0q.y + vz * a0q.z + vw * a0q.w;
        float p1 = vx * a1q.x + vy * a1q.y + vz * a1q.z + vw * a1q.w;
        p0 = red16(p0);
        p1 = red16(p1);
        float e0 = 0.25f * __expf(p0), e1 = 0.25f * __expf(p1);
        s0 = e0; s1 = e1;
        A0.x = e0 * hd.x; A0.y = e0 * hd.y; A0.z = e0 * hd.z; A0.w = e0 * hd.w;
        A1.x = e1 * hd.x; A1.y = e1 * hd.y; A1.z = e1 * hd.z; A1.w = e1 * hd.w;
    }

    // main loop: subgroup takes edge pairs (2p, 2p+1) — one u32 = both indices
    int npair = deg >> 1;
    for (int p = sub; p < npair; p += 4) {
        unsigned pk = rowu[p];
        float4 va = *(const float4*)(hb + (((pk & 0xFFFFu) << 8) + qb));
        float4 vb = *(const float4*)(hb + (((pk >> 16) << 8) + qb));
        float vx, vy, vz, vw;
        vx = LEAKY(va.x + hd.x); vy = LEAKY(va.y + hd.y);
        vz = LEAKY(va.z + hd.z); vw = LEAKY(va.w + hd.w);
        float pa0 = vx * a0q.x + vy * a0q.y + vz * a0q.z + vw * a0q.w;
        float pa1 = vx * a1q.x + vy * a1q.y + vz * a1q.z + vw * a1q.w;
        vx = LEAKY(vb.x + hd.x); vy = LEAKY(vb.y + hd.y);
        vz = LEAKY(vb.z + hd.z); vw = LEAKY(vb.w + hd.w);
        float pb0 = vx * a0q.x + vy * a0q.y + vz * a0q.z + vw * a0q.w;
        float pb1 = vx * a1q.x + vy * a1q.y + vz * a1q.z + vw * a1q.w;
        pa0 = red16(pa0); pa1 = red16(pa1);
        pb0 = red16(pb0); pb1 = red16(pb1);
        float ea0 = __expf(pa0), ea1 = __expf(pa1);
        float eb0 = __expf(pb0), eb1 = __expf(pb1);
        s0 += ea0 + eb0;
        s1 += ea1 + eb1;
        A0.x += ea0 * va.x + eb0 * vb.x; A0.y += ea0 * va.y + eb0 * vb.y;
        A0.z += ea0 * va.z + eb0 * vb.z; A0.w += ea0 * va.w + eb0 * vb.w;
        A1.x += ea1 * va.x + eb1 * vb.x; A1.y += ea1 * va.y + eb1 * vb.y;
        A1.z += ea1 * va.z + eb1 * vb.z; A1.w += ea1 * va.w + eb1 * vb.w;
    }

    // tail: one odd edge, handled by one subgroup (uniform per subgroup)
    if (deg & 1) {
        int t = deg - 1;
        if (sub == ((t >> 1) & 3)) {
            unsigned s = ((const unsigned short*)rowu)[t];
            float4 hv = *(const float4*)(hb + ((s << 8) + qb));
            float vx = LEAKY(hv.x + hd.x), vy = LEAKY(hv.y + hd.y);
            float vz = LEAKY(hv.z + hd.z), vw = LEAKY(hv.w + hd.w);
            float p0 = vx * a0q.x + vy * a0q.y + vz * a0q.z + vw * a0q.w;
            float p1 = vx * a1q.x + vy * a1q.y + vz * a1q.z + vw * a1q.w;
            p0 = red16(p0);
            p1 = red16(p1);
            float e0 = __expf(p0), e1 = __expf(p1);
            s0 += e0; s1 += e1;
            A0.x += e0 * hv.x; A0.y += e0 * hv.y; A0.z += e0 * hv.z; A0.w += e0 * hv.w;
            A1.x += e1 * hv.x; A1.y += e1 * hv.y; A1.z += e1 * hv.z; A1.w += e1 * hv.w;
        }
    }

    // merge the 4 subgroups: plain sums (cross-row — DPP can't, keep shfl)
#pragma unroll
    for (int step = 16; step <= 32; step <<= 1) {
        s0 += __shfl_xor(s0, step);
        s1 += __shfl_xor(s1, step);
        A0.x += __shfl_xor(A0.x, step); A0.y += __shfl_xor(A0.y, step);
        A0.z += __shfl_xor(A0.z, step); A0.w += __shfl_xor(A0.w, step);
        A1.x += __shfl_xor(A1.x, step); A1.y += __shfl_xor(A1.y, step);
        A1.z += __shfl_xor(A1.z, step); A1.w += __shfl_xor(A1.w, step);
    }

    if (sub == 0) {
        float inv0 = 0.5f / (s0 + 1e-16f);       // fold mean-over-heads
        float inv1 = 0.5f / (s1 + 1e-16f);
        float4 b4 = ((const float4*)bias_l)[q];
        float4 o;
        o.x = A0.x * inv0 + A1.x * inv1 + b4.x;
        o.y = A0.y * inv0 + A1.y * inv1 + b4.y;
        o.z = A0.z * inv0 + A1.z * inv1 + b4.z;
        o.w = A0.w * inv0 + A1.w * inv1 + b4.w;
        ((float4*)h_out)[(size_t)node * 16 + q] = o;
        float4* accp = (float4*)acc + (size_t)node * 16 + q;
        float4 ac;
        if (FIRST) {
            // acc = 0.25*(x + h1); hd holds x's row quad
            ac.x = 0.25f * (hd.x + o.x); ac.y = 0.25f * (hd.y + o.y);
            ac.z = 0.25f * (hd.z + o.z); ac.w = 0.25f * (hd.w + o.w);
        } else {
            ac = *accp;
            ac.x += 0.25f * o.x; ac.y += 0.25f * o.y;
            ac.z += 0.25f * o.z; ac.w += 0.25f * o.w;
        }
        *accp = ac;
    }
}

// ---------------- launch ----------------

static inline size_t align256(size_t x) { return (x + 255) & ~(size_t)255; }

extern "C" void kernel_launch(void* const* d_in, const int* in_sizes, int n_in,
                              void* d_out, int out_size, void* d_ws, size_t ws_size,
                              hipStream_t stream) {
    const float* x    = (const float*)d_in[0];
    const int*   ei   = (const int*)d_in[1];
    const float* att  = (const float*)d_in[2];
    const float* bias = (const float*)d_in[3];
    float* acc = (float*)d_out;   // fp32 output; feats-mean accumulated here

    char* w = (char*)d_ws;
    int* cnt    = (int*)w;              w += align256((size_t)NN * sizeof(int));
    unsigned short* slots = (unsigned short*)w;
    w += align256((size_t)NN * CAP * sizeof(unsigned short));
    float* hA   = (float*)w;            w += align256((size_t)NN * CC * sizeof(float));
    float* hB   = (float*)w;            w += align256((size_t)NN * CC * sizeof(float));

    const int B = 256;

    // build (per call; ws is re-poisoned before every launch)
    hipMemsetAsync(cnt, 0, (size_t)NN * sizeof(int), stream);
    k_build<<<(EE + B - 1) / B, B, 0, stream>>>(ei, cnt, slots);

    // 3 fused GAT layers; layer 0 reads x directly and seeds acc = 0.25*(x + h1)
    k_gat<true><<<(NN + 3) / 4, B, 0, stream>>>(
        x, cnt, slots, att, bias, hA, acc, NN);
    k_gat<false><<<(NN + 3) / 4, B, 0, stream>>>(
        hA, cnt, slots, att + (size_t)HH * CC, bias + CC, hB, acc, NN);
    k_gat<false><<<(NN + 3) / 4, B, 0, stream>>>(
        hB, cnt, slots, att + (size_t)2 * HH * CC, bias + 2 * CC, hA, acc, NN);
}